// Round 4
// baseline (14350.618 us; speedup 1.0000x reference)
//
#include <hip/hip_runtime.h>
#include <math.h>

#define N_VEC   8192
#define EDIM    768
#define NCODES  1024
#define SKITERS 100
#define ROWS_PB 32
#define SK_THR  512
#define CHUNKS  (N_VEC / ROWS_PB)   // 256

// ---------- numpy pairwise sum-of-squares over 768 contiguous f32 ----------
__device__ __forceinline__ float np_base96_sq(const float* a) {
  float r[8];
#pragma unroll
  for (int j = 0; j < 8; ++j) r[j] = __fmul_rn(a[j], a[j]);
  for (int i = 8; i < 96; i += 8) {
#pragma unroll
    for (int j = 0; j < 8; ++j) r[j] = __fadd_rn(r[j], __fmul_rn(a[i + j], a[i + j]));
  }
  float c01 = __fadd_rn(r[0], r[1]);
  float c23 = __fadd_rn(r[2], r[3]);
  float c45 = __fadd_rn(r[4], r[5]);
  float c67 = __fadd_rn(r[6], r[7]);
  return __fadd_rn(__fadd_rn(c01, c23), __fadd_rn(c45, c67));
}
__device__ __forceinline__ float np_ssq768(const float* a) {
  float L[8];
#pragma unroll
  for (int t = 0; t < 8; ++t) L[t] = np_base96_sq(a + 96 * t);
  float a01 = __fadd_rn(L[0], L[1]);
  float a23 = __fadd_rn(L[2], L[3]);
  float a45 = __fadd_rn(L[4], L[5]);
  float a67 = __fadd_rn(L[6], L[7]);
  return __fadd_rn(__fadd_rn(a01, a23), __fadd_rn(a45, a67));
}

// one thread per row
__global__ __launch_bounds__(64) void rows_ssq(const float* __restrict__ a,
                                               float* __restrict__ out, int nrows) {
  int row = blockIdx.x * 64 + threadIdx.x;
  if (row < nrows) out[row] = np_ssq768(a + (size_t)row * EDIM);
}

// ---------- GEMM: dot = sequential ascending-k f32 FMA chain; assemble d / lq0 ----------
#define BM 128
#define BN 128
#define BK 16
template <bool LAYER0>
__global__ __launch_bounds__(256) void gemm_d(const float* __restrict__ A,   // residual [N][768]
                                              const float* __restrict__ B,   // codebook [K][768]
                                              const float* __restrict__ sumrr,
                                              const float* __restrict__ sumee,
                                              float* __restrict__ V) {       // d (L0) or lq0
  __shared__ float As[BK][BM];
  __shared__ float Bs[BK][BN];
  int tid = threadIdx.x;
  int bm = blockIdx.y * BM;
  int bn = blockIdx.x * BN;
  int lr = tid >> 1;             // 0..127
  int lc = (tid & 1) << 3;       // 0 or 8
  const float* Ap = A + (size_t)(bm + lr) * EDIM + lc;
  const float* Bp = B + (size_t)(bn + lr) * EDIM + lc;
  float acc[8][8];
#pragma unroll
  for (int i = 0; i < 8; ++i)
#pragma unroll
    for (int j = 0; j < 8; ++j) acc[i][j] = 0.f;
  int ty = tid >> 4, tx = tid & 15;
  for (int k0 = 0; k0 < EDIM; k0 += BK) {
    float4 a0 = *(const float4*)(Ap + k0);
    float4 a1 = *(const float4*)(Ap + k0 + 4);
    float4 b0 = *(const float4*)(Bp + k0);
    float4 b1 = *(const float4*)(Bp + k0 + 4);
    __syncthreads();
    As[lc + 0][lr] = a0.x; As[lc + 1][lr] = a0.y; As[lc + 2][lr] = a0.z; As[lc + 3][lr] = a0.w;
    As[lc + 4][lr] = a1.x; As[lc + 5][lr] = a1.y; As[lc + 6][lr] = a1.z; As[lc + 7][lr] = a1.w;
    Bs[lc + 0][lr] = b0.x; Bs[lc + 1][lr] = b0.y; Bs[lc + 2][lr] = b0.z; Bs[lc + 3][lr] = b0.w;
    Bs[lc + 4][lr] = b1.x; Bs[lc + 5][lr] = b1.y; Bs[lc + 6][lr] = b1.z; Bs[lc + 7][lr] = b1.w;
    __syncthreads();
#pragma unroll
    for (int k = 0; k < BK; ++k) {   // ascending k: sequential FMA chain per (i,j)
      float av[8], bv[8];
      *(float4*)(av)     = *(const float4*)(&As[k][ty * 8]);
      *(float4*)(av + 4) = *(const float4*)(&As[k][ty * 8 + 4]);
      *(float4*)(bv)     = *(const float4*)(&Bs[k][tx * 8]);
      *(float4*)(bv + 4) = *(const float4*)(&Bs[k][tx * 8 + 4]);
#pragma unroll
      for (int i = 0; i < 8; ++i)
#pragma unroll
        for (int j = 0; j < 8; ++j) acc[i][j] = __fmaf_rn(av[i], bv[j], acc[i][j]);
    }
  }
#pragma unroll
  for (int i = 0; i < 8; ++i) {
    int row = bm + ty * 8 + i;
    float srr = sumrr[row];
    float* Vp = V + (size_t)row * NCODES + bn + tx * 8;
#pragma unroll
    for (int j = 0; j < 8; ++j) {
      int col = bn + tx * 8 + j;
      float s1 = __fadd_rn(srr, sumee[col]);
      float dv = __fsub_rn(s1, __fmul_rn(2.0f, acc[i][j]));
      Vp[j] = LAYER0 ? dv : __fdiv_rn(-dv, 0.003f);
    }
  }
}

// ---------- online f32 LSE helpers (order noise absorbed by np's rounding grids) ----------
__device__ __forceinline__ void accf(float w, float& m, float& s) {
  if (w > m) { s = __fadd_rn(__fmul_rn(s, expf(__fsub_rn(m, w))), 1.0f); m = w; }
  else       { s = __fadd_rn(s, expf(__fsub_rn(w, m))); }
}
__device__ __forceinline__ void mergef(float mo, float so, float& m, float& s) {
  float mn = fmaxf(m, mo);
  if (mn == -INFINITY) { s = 0.f; return; }
  float e0 = (m  == -INFINITY) ? 0.f : __fmul_rn(s,  expf(__fsub_rn(m,  mn)));
  float e1 = (mo == -INFINITY) ? 0.f : __fmul_rn(so, expf(__fsub_rn(mo, mn)));
  s = __fadd_rn(e0, e1);
  m = mn;
}

// ---------- sk_row: apply colL, row-LSE + subtract (in place), emit col partials ----------
template <bool DO_ROW>
__global__ __launch_bounds__(SK_THR) void sk_row(float* __restrict__ lq,
                                                 const float* __restrict__ colL,
                                                 float* __restrict__ partM,
                                                 float* __restrict__ partS) {
  int tid = threadIdx.x;
  int r0 = blockIdx.x * ROWS_PB;
  if (DO_ROW) {
    int wave = tid >> 6, lane = tid & 63;
#pragma unroll
    for (int rr = 0; rr < 4; ++rr) {
      int row = r0 + wave * 4 + rr;
      float* R = lq + (size_t)row * NCODES;
      float v[16];
      float mx = -INFINITY;
#pragma unroll
      for (int k = 0; k < 16; ++k) {
        int c = lane + (k << 6);
        v[k] = __fsub_rn(R[c], colL[c]);      // completes column normalization
        mx = fmaxf(mx, v[k]);
      }
      for (int off = 32; off; off >>= 1) mx = fmaxf(mx, __shfl_xor(mx, off, 64));
      float s = 0.f;
#pragma unroll
      for (int k = 0; k < 16; ++k) s = __fadd_rn(s, expf(__fsub_rn(v[k], mx)));
      for (int off = 32; off; off >>= 1) s = __fadd_rn(s, __shfl_xor(s, off, 64));
      float rowL = __fadd_rn(logf(s), mx);    // scipy: log(sum) + amax
#pragma unroll
      for (int k = 0; k < 16; ++k) {
        int c = lane + (k << 6);
        R[c] = __fsub_rn(v[k], rowL);         // row normalization, written back
      }
    }
  }
  __syncthreads();
  // column partials over this block's 32 (updated) rows
  float m0 = -INFINITY, s0 = 0.f, m1 = -INFINITY, s1v = 0.f;
  int c0 = tid, c1 = tid + SK_THR;
  const float* Bk = lq + (size_t)r0 * NCODES;
  for (int r = 0; r < ROWS_PB; ++r) {
    accf(Bk[(size_t)r * NCODES + c0], m0, s0);
    accf(Bk[(size_t)r * NCODES + c1], m1, s1v);
  }
  partM[(size_t)blockIdx.x * NCODES + c0] = m0;
  partM[(size_t)blockIdx.x * NCODES + c1] = m1;
  partS[(size_t)blockIdx.x * NCODES + c0] = s0;
  partS[(size_t)blockIdx.x * NCODES + c1] = s1v;
}

// ---------- merge column partials -> colL ----------
__global__ __launch_bounds__(256) void colmerge(const float* __restrict__ partM,
                                                const float* __restrict__ partS,
                                                float* __restrict__ colL) {
  int tid = threadIdx.x;
  int cl = tid & 31;
  int grp = tid >> 5;   // 0..7
  int col = blockIdx.x * 32 + cl;
  float m = -INFINITY, s = 0.f;
  for (int q = 0; q < CHUNKS / 8; ++q) {
    int chunk = grp * (CHUNKS / 8) + q;
    mergef(partM[(size_t)chunk * NCODES + col], partS[(size_t)chunk * NCODES + col], m, s);
  }
  __shared__ float Ms[8][32], Ss[8][32];
  Ms[grp][cl] = m; Ss[grp][cl] = s;
  __syncthreads();
  if (grp == 0) {
#pragma unroll
    for (int q = 1; q < 8; ++q) mergef(Ms[q][cl], Ss[q][cl], m, s);
    colL[col] = __fadd_rn(logf(s), m);        // scipy: log(sum) + amax
  }
}

// ---------- epilogue: argmin(d) / argmax(lq), gather, f32 residual, ssq ----------
template <int MODE>   // 0: argmin, 1: argmax
__global__ __launch_bounds__(256) void epi(const float* __restrict__ V,
                                           const float* __restrict__ rin,
                                           const float* __restrict__ cb,
                                           float* __restrict__ rout,
                                           double* __restrict__ rowssq,
                                           float* __restrict__ idx_out,
                                           int layer) {
  int i = blockIdx.x;
  int tid = threadIdx.x;
  const float* Vrow = V + (size_t)i * NCODES;
  float bv = MODE ? -INFINITY : INFINITY;
  int bj = 0;
  for (int j = tid; j < NCODES; j += 256) {
    float v = Vrow[j];
    bool better = MODE ? (v > bv) : (v < bv);   // strict: first occurrence kept
    if (better) { bv = v; bj = j; }
  }
  __shared__ float sv[256];
  __shared__ int   sj[256];
  sv[tid] = bv; sj[tid] = bj;
  __syncthreads();
  for (int st = 128; st; st >>= 1) {
    if (tid < st) {
      float v2 = sv[tid + st]; int j2 = sj[tid + st];
      bool better = MODE ? (v2 > sv[tid]) : (v2 < sv[tid]);
      if (better || (v2 == sv[tid] && j2 < sj[tid])) { sv[tid] = v2; sj[tid] = j2; }
    }
    __syncthreads();
  }
  int idx = sj[0];
  const float* crow = cb + (size_t)idx * EDIM;
  double p = 0.0;
  for (int c = tid; c < EDIM; c += 256) {
    float rn = __fsub_rn(rin[(size_t)i * EDIM + c], crow[c]);
    rout[(size_t)i * EDIM + c] = rn;
    p += (double)rn * (double)rn;
  }
  for (int off = 32; off; off >>= 1) p += __shfl_xor(p, off, 64);
  __shared__ double wsum[4];
  if ((tid & 63) == 0) wsum[tid >> 6] = p;
  __syncthreads();
  if (tid == 0) {
    rowssq[i] = wsum[0] + wsum[1] + wsum[2] + wsum[3];
    idx_out[(size_t)i * 4 + layer] = (float)idx;
  }
}

// ---------- final loss ----------
__global__ __launch_bounds__(1024) void loss_final(const double* __restrict__ rowssq,
                                                   float* __restrict__ out_loss) {
  int tid = threadIdx.x;
  __shared__ double acc[16];
  __shared__ double ltot;
  if (tid == 0) ltot = 0.0;
  __syncthreads();
  for (int l = 0; l < 4; ++l) {
    double p = 0.0;
    for (int i = tid; i < N_VEC; i += 1024) p += rowssq[l * N_VEC + i];
    for (int off = 32; off; off >>= 1) p += __shfl_xor(p, off, 64);
    if ((tid & 63) == 0) acc[tid >> 6] = p;
    __syncthreads();
    if (tid == 0) {
      double sl = 0.0;
      for (int w = 0; w < 16; ++w) sl += acc[w];
      ltot += 2.0 * sl / ((double)N_VEC * (double)EDIM);
    }
    __syncthreads();
  }
  if (tid == 0) out_loss[0] = (float)(ltot * 0.25);
}

// ---------- x_q = x - resid ----------
__global__ __launch_bounds__(256) void xq_final(const float* __restrict__ x,
                                                float* __restrict__ out) {
  size_t i = ((size_t)blockIdx.x * 256 + threadIdx.x) * 4;
  float4 xv = *(const float4*)(x + i);
  float4 rv = *(const float4*)(out + i);
  float4 o;
  o.x = __fsub_rn(xv.x, rv.x); o.y = __fsub_rn(xv.y, rv.y);
  o.z = __fsub_rn(xv.z, rv.z); o.w = __fsub_rn(xv.w, rv.w);
  *(float4*)(out + i) = o;
}

extern "C" void kernel_launch(void* const* d_in, const int* in_sizes, int n_in,
                              void* d_out, int out_size, void* d_ws, size_t ws_size,
                              hipStream_t stream) {
  const float* x = (const float*)d_in[0];
  const float* cbs[4] = {(const float*)d_in[1], (const float*)d_in[2],
                         (const float*)d_in[3], (const float*)d_in[4]};
  float* out = (float*)d_out;
  float* resid = out;                                   // reuse x_q region as residual
  float* loss_out = out + (size_t)N_VEC * EDIM;
  float* idx_out = loss_out + 1;

  float* ws = (float*)d_ws;
  float* lq    = ws;                                    // N*K f32      (32 MB)
  float* partM = lq + (size_t)N_VEC * NCODES;           // CHUNKS*K     (1 MB)
  float* partS = partM + (size_t)CHUNKS * NCODES;       // CHUNKS*K     (1 MB)
  float* colL  = partS + (size_t)CHUNKS * NCODES;       // K
  float* sumrr = colL + NCODES;                         // N
  float* sumee = sumrr + N_VEC;                         // 4*K
  double* rowssq = (double*)(sumee + 4 * NCODES);       // 4*N doubles (offset is 8-aligned)

  for (int l = 0; l < 4; ++l)
    rows_ssq<<<NCODES / 64, 64, 0, stream>>>(cbs[l], sumee + l * NCODES, NCODES);
  rows_ssq<<<N_VEC / 64, 64, 0, stream>>>(x, sumrr, N_VEC);

  for (int l = 0; l < 4; ++l) {
    const float* rin = (l == 0) ? x : resid;
    if (l == 0) {
      gemm_d<true><<<dim3(NCODES / BN, N_VEC / BM), 256, 0, stream>>>(rin, cbs[l], sumrr, sumee + l * NCODES, lq);
      epi<0><<<N_VEC, 256, 0, stream>>>(lq, rin, cbs[l], resid, rowssq + (size_t)l * N_VEC, idx_out, l);
    } else {
      gemm_d<false><<<dim3(NCODES / BN, N_VEC / BM), 256, 0, stream>>>(rin, cbs[l], sumrr, sumee + l * NCODES, lq);
      sk_row<false><<<CHUNKS, SK_THR, 0, stream>>>(lq, nullptr, partM, partS);
      for (int t = 0; t < SKITERS; ++t) {
        colmerge<<<NCODES / 32, 256, 0, stream>>>(partM, partS, colL);
        sk_row<true><<<CHUNKS, SK_THR, 0, stream>>>(lq, colL, partM, partS);
      }
      epi<1><<<N_VEC, 256, 0, stream>>>(lq, rin, cbs[l], resid, rowssq + (size_t)l * N_VEC, idx_out, l);
    }
    if (l < 3)
      rows_ssq<<<N_VEC / 64, 64, 0, stream>>>(resid, sumrr, N_VEC);
  }
  loss_final<<<1, 1024, 0, stream>>>(rowssq, loss_out);
  xq_final<<<(N_VEC * EDIM / 4) / 256, 256, 0, stream>>>(x, out);
}